// Round 6
// baseline (187.092 us; speedup 1.0000x reference)
//
#include <hip/hip_runtime.h>

// SpectralRewiringLayer. Factorized: h1 = relu(u[src] + v[dst]),
//   u[n] = W1[0:64]^T emb[n] + b1 + fied[n]*W1[128]
//   v[n] = W1[64:128]^T emb[n] + fied[n]*W1[129]
// fp16 storage for u,v. K1: MFMA GEMM precompute. K2: gather-bound edge MLP;
// currency = outstanding gather lines/CU. Depth-3 pipeline, indices one
// iteration ahead (vmcnt retires in order — R3 lesson), W2 frags in LDS
// (VGPR diet -> more waves), packed-fp16 epilogue with v_dot2_f32_f16.

#define HD 64

typedef __attribute__((ext_vector_type(8))) _Float16 half8;
typedef __attribute__((ext_vector_type(4))) _Float16 half4;
typedef __attribute__((ext_vector_type(2))) _Float16 half2v;
typedef __attribute__((ext_vector_type(8))) short  short8;
typedef __attribute__((ext_vector_type(2))) short  short2v;
typedef __attribute__((ext_vector_type(8))) float  float8;
typedef __attribute__((ext_vector_type(4))) float  f32x4;

__device__ __forceinline__ half8 relu_h8(half8 x) {
    short8 b = __builtin_bit_cast(short8, x);
    short8 m = b >> 15;
    b = b & ~m;
    return __builtin_bit_cast(half8, b);
}
__device__ __forceinline__ half2v relu_h2(half2v x) {
    short2v b = __builtin_bit_cast(short2v, x);
    short2v m = b >> 15;
    b = b & ~m;
    return __builtin_bit_cast(half2v, b);
}
__device__ __forceinline__ half2v pkrtz(float a, float b) {
    return __builtin_bit_cast(half2v, __builtin_amdgcn_cvt_pkrtz(a, b));
}

// ---------------- K1: u,v precompute, transposed MFMA GEMM ----------------
__global__ __launch_bounds__(256) void precompute_uv(
    const float* __restrict__ emb, const float* __restrict__ fied,
    const float* __restrict__ W1, const float* __restrict__ b1,
    _Float16* __restrict__ u, _Float16* __restrict__ v,
    int n_nodes, int ntiles)
{
    const int lane = threadIdx.x & 63;
    const int q = lane >> 4;
    const int c = lane & 15;
    const int wid = blockIdx.x * (blockDim.x >> 6) + (threadIdx.x >> 6);
    const int nw  = gridDim.x * (blockDim.x >> 6);

    half8 Au[4][2], Av[4][2];
    #pragma unroll
    for (int t = 0; t < 4; ++t)
        #pragma unroll
        for (int ks = 0; ks < 2; ++ks)
            #pragma unroll
            for (int j = 0; j < 8; ++j) {
                int k = ks * 32 + q * 8 + j;
                Au[t][ks][j] = (_Float16)W1[k * HD + t * 16 + c];
                Av[t][ks][j] = (_Float16)W1[(64 + k) * HD + t * 16 + c];
            }
    f32x4 b1q[4], wsq[4], wdq[4];
    #pragma unroll
    for (int t = 0; t < 4; ++t) {
        b1q[t] = *(const f32x4*)(b1 + t * 16 + q * 4);
        wsq[t] = *(const f32x4*)(W1 + 128 * HD + t * 16 + q * 4);
        wdq[t] = *(const f32x4*)(W1 + 129 * HD + t * 16 + q * 4);
    }

    for (int tile = wid; tile < ntiles; tile += nw) {
        const int n0 = tile * 16;
        const int n  = n0 + c;
        int na = n; if (na >= n_nodes) na = n_nodes - 1;
        const float* rp = emb + (size_t)na * HD + q * 8;
        float8 a0 = *(const float8*)rp;
        float8 a1 = *(const float8*)(rp + 32);
        half8 B0 = __builtin_convertvector(a0, half8);
        half8 B1 = __builtin_convertvector(a1, half8);

        f32x4 aU[4] = {}, aV[4] = {};
        #pragma unroll
        for (int t = 0; t < 4; ++t) {
            aU[t] = __builtin_amdgcn_mfma_f32_16x16x32_f16(Au[t][0], B0, aU[t], 0, 0, 0);
            aU[t] = __builtin_amdgcn_mfma_f32_16x16x32_f16(Au[t][1], B1, aU[t], 0, 0, 0);
            aV[t] = __builtin_amdgcn_mfma_f32_16x16x32_f16(Av[t][0], B0, aV[t], 0, 0, 0);
            aV[t] = __builtin_amdgcn_mfma_f32_16x16x32_f16(Av[t][1], B1, aV[t], 0, 0, 0);
        }

        const float fv = fied[na];
        const bool ok = (n < n_nodes);
        #pragma unroll
        for (int t = 0; t < 4; ++t) {
            half4 hu, hv;
            #pragma unroll
            for (int r = 0; r < 4; ++r) {
                hu[r] = (_Float16)(aU[t][r] + b1q[t][r] + fv * wsq[t][r]);
                hv[r] = (_Float16)(aV[t][r] + fv * wdq[t][r]);
            }
            if (ok) {
                *(half4*)(u + (size_t)n * HD + t * 16 + q * 4) = hu;
                *(half4*)(v + (size_t)n * HD + t * 16 + q * 4) = hv;
            }
        }
    }
}

// ---------------- K2: per-edge MLP (layers 2+3) ----------------
// D' = W2^T . h1^T : A = W2^T (in LDS), B = h1^T (gathered).
// D' layout: col = c = edge, row = q*4+r = feature t*16+q*4+r.
__global__ __launch_bounds__(256) void edge_mlp(
    const _Float16* __restrict__ u, const _Float16* __restrict__ v,
    const int* __restrict__ src, const int* __restrict__ dst,
    const float* __restrict__ W2, const float* __restrict__ b2,
    const float* __restrict__ W3, const float* __restrict__ b3,
    float* __restrict__ out, int E, int ntiles)
{
    const int tid  = threadIdx.x;
    const int lane = tid & 63;
    const int q = lane >> 4;
    const int c = lane & 15;
    const int wid = blockIdx.x * (blockDim.x >> 6) + (tid >> 6);
    const int nw  = gridDim.x * (blockDim.x >> 6);

    // W2^T A-fragments in LDS: AfL[t][ks][q*16+c] (half8 each).
    __shared__ half8 AfL[4][2][64];
    for (int i = tid; i < 512; i += 256) {
        const int t = i >> 7, ks = (i >> 6) & 1, qc = i & 63;
        const int qq = qc >> 4, cc = qc & 15;
        half8 val;
        #pragma unroll
        for (int j = 0; j < 8; ++j) {
            int k = ks * 32 + qq * 8 + j;
            val[j] = (_Float16)W2[k * HD + t * 16 + cc];
        }
        AfL[t][ks][qc] = val;
    }
    __syncthreads();

    // epilogue consts as packed half2 (features f = t*16 + q*4 + r)
    half2v b2p[4][2], w3p[4][2];
    #pragma unroll
    for (int t = 0; t < 4; ++t) {
        int f = t * 16 + q * 4;
        b2p[t][0] = half2v{(_Float16)b2[f],     (_Float16)b2[f + 1]};
        b2p[t][1] = half2v{(_Float16)b2[f + 2], (_Float16)b2[f + 3]};
        w3p[t][0] = half2v{(_Float16)W3[f],     (_Float16)W3[f + 1]};
        w3p[t][1] = half2v{(_Float16)W3[f + 2], (_Float16)W3[f + 3]};
    }
    const float b3v = b3[0];

    auto eid = [&](int tile) {
        int t = tile; if (t >= ntiles) t = ntiles - 1;
        int e = t * 16 + c; if (e >= E) e = E - 1;
        return e;
    };
    auto issue = [&](int s, int d, half8& Ua, half8& Ub, half8& Va, half8& Vb) {
        const half8* up = (const half8*)(u + (unsigned)s * HD + q * 8);
        const half8* vp = (const half8*)(v + (unsigned)d * HD + q * 8);
        Ua = up[0]; Ub = up[4]; Va = vp[0]; Vb = vp[4];
    };
    auto compute_store = [&](int tile, half8 Ua, half8 Ub, half8 Va, half8 Vb) {
        half8 B0 = relu_h8(Ua + Va);
        half8 B1 = relu_h8(Ub + Vb);
        // launder LDS index so the 8 ds_reads can't be hoisted out of the loop
        unsigned qc = (unsigned)(q * 16 + c);
        asm("" : "+v"(qc));
        float p = 0.f;
        #pragma unroll
        for (int t = 0; t < 4; ++t) {
            f32x4 acc = {};
            acc = __builtin_amdgcn_mfma_f32_16x16x32_f16(AfL[t][0][qc], B0, acc, 0, 0, 0);
            acc = __builtin_amdgcn_mfma_f32_16x16x32_f16(AfL[t][1][qc], B1, acc, 0, 0, 0);
            half2v h0 = pkrtz(acc[0], acc[1]);
            half2v h1 = pkrtz(acc[2], acc[3]);
            h0 = relu_h2(h0 + b2p[t][0]);
            h1 = relu_h2(h1 + b2p[t][1]);
            p = __builtin_amdgcn_fdot2(__builtin_bit_cast(__fp16 __attribute__((ext_vector_type(2))), h0),
                                       __builtin_bit_cast(__fp16 __attribute__((ext_vector_type(2))), w3p[t][0]), p, false);
            p = __builtin_amdgcn_fdot2(__builtin_bit_cast(__fp16 __attribute__((ext_vector_type(2))), h1),
                                       __builtin_bit_cast(__fp16 __attribute__((ext_vector_type(2))), w3p[t][1]), p, false);
        }
        p += __shfl_xor(p, 16, 64);
        p += __shfl_xor(p, 32, 64);
        if (q == 0) {
            int e = tile * 16 + c;
            if (e < E) out[e] = p + b3v;
        }
    };

    const int stride = nw * 3;
    const int base0  = wid * 3;
    if (base0 >= ntiles) return;

    // ---- prologue ----
    int e0 = eid(base0), e1 = eid(base0 + 1), e2 = eid(base0 + 2);
    int s0 = src[e0], d0 = dst[e0];
    int s1 = src[e1], d1 = dst[e1];
    int s2 = src[e2], d2 = dst[e2];
    half8 U0a, U0b, V0a, V0b, U1a, U1b, V1a, V1b, U2a, U2b, V2a, V2b;
    issue(s0, d0, U0a, U0b, V0a, V0b);
    issue(s1, d1, U1a, U1b, V1a, V1b);
    issue(s2, d2, U2a, U2b, V2a, V2b);
    // idx_cur: indices for the refills issued during the NEXT loop body
    int f0 = eid(base0 + stride), f1 = eid(base0 + stride + 1), f2 = eid(base0 + stride + 2);
    int sc0 = src[f0], dc0 = dst[f0];
    int sc1 = src[f1], dc1 = dst[f1];
    int sc2 = src[f2], dc2 = dst[f2];

    for (int base = base0; base < ntiles; base += stride) {
        const int g0 = eid(base + 2 * stride), g1 = eid(base + 2 * stride + 1),
                  g2 = eid(base + 2 * stride + 2);
        const int sn0 = src[g0], dn0 = dst[g0];
        const int sn1 = src[g1], dn1 = dst[g1];
        const int sn2 = src[g2], dn2 = dst[g2];

        compute_store(base,     U0a, U0b, V0a, V0b);
        issue(sc0, dc0, U0a, U0b, V0a, V0b);
        compute_store(base + 1, U1a, U1b, V1a, V1b);
        issue(sc1, dc1, U1a, U1b, V1a, V1b);
        compute_store(base + 2, U2a, U2b, V2a, V2b);
        issue(sc2, dc2, U2a, U2b, V2a, V2b);

        sc0 = sn0; dc0 = dn0; sc1 = sn1; dc1 = dn1; sc2 = sn2; dc2 = dn2;
    }
}

extern "C" void kernel_launch(void* const* d_in, const int* in_sizes, int n_in,
                              void* d_out, int out_size, void* d_ws, size_t ws_size,
                              hipStream_t stream) {
    const float* emb  = (const float*)d_in[0];
    const float* fied = (const float*)d_in[1];
    const float* W1   = (const float*)d_in[2];
    const float* b1   = (const float*)d_in[3];
    const float* W2   = (const float*)d_in[4];
    const float* b2   = (const float*)d_in[5];
    const float* W3   = (const float*)d_in[6];
    const float* b3   = (const float*)d_in[7];
    const int*   eidx = (const int*)d_in[8];

    const int n_nodes = in_sizes[1];
    const int E       = in_sizes[8] / 2;
    const int* srcp = eidx;
    const int* dstp = eidx + E;

    _Float16* u = (_Float16*)d_ws;                 // n_nodes*64 fp16
    _Float16* v = u + (size_t)n_nodes * HD;        // n_nodes*64 fp16

    const int ntilesN = (n_nodes + 15) / 16;
    precompute_uv<<<1024, 256, 0, stream>>>(emb, fied, W1, b1, u, v,
                                            n_nodes, ntilesN);

    const int ntilesE = (E + 15) / 16;
    edge_mlp<<<4096, 256, 0, stream>>>(u, v, srcp, dstp, W2, b2, W3, b3,
                                       (float*)d_out, E, ntilesE);
}

// Round 7
// 183.700 us; speedup vs baseline: 1.0185x; 1.0185x over previous
//
#include <hip/hip_runtime.h>

// SpectralRewiringLayer. Factorized: h1 = relu(u[src] + v[dst]),
//   u[n] = W1[0:64]^T emb[n] + b1 + fied[n]*W1[128]
//   v[n] = W1[64:128]^T emb[n] + fied[n]*W1[129]
// fp16 u,v. K1: MFMA GEMM precompute. K2: gather-bound edge MLP.
// Session model: dur ~ 1/(waves x gather-lines-in-flight/wave).
// R6 lesson: VGPR_Count is the pipeline-integrity diagnostic — LDS frags +
// asm laundering made the scheduler collapse the pipeline (52 VGPR). R7:
// register-held W2 frags (R4-proven), packed-fp16 epilogue (VGPR diet),
// depth-4 pipeline, indices one iteration ahead (vmcnt retires in order).

#define HD 64

typedef __attribute__((ext_vector_type(8))) _Float16 half8;
typedef __attribute__((ext_vector_type(4))) _Float16 half4;
typedef __attribute__((ext_vector_type(2))) _Float16 half2v;
typedef __attribute__((ext_vector_type(2))) __fp16  fp16x2;
typedef __attribute__((ext_vector_type(8))) short  short8;
typedef __attribute__((ext_vector_type(2))) short  short2v;
typedef __attribute__((ext_vector_type(8))) float  float8;
typedef __attribute__((ext_vector_type(4))) float  f32x4;

__device__ __forceinline__ half8 relu_h8(half8 x) {
    short8 b = __builtin_bit_cast(short8, x);
    short8 m = b >> 15;
    b = b & ~m;
    return __builtin_bit_cast(half8, b);
}
__device__ __forceinline__ half2v relu_h2(half2v x) {
    short2v b = __builtin_bit_cast(short2v, x);
    short2v m = b >> 15;
    b = b & ~m;
    return __builtin_bit_cast(half2v, b);
}
__device__ __forceinline__ half2v pkrtz(float a, float b) {
    return __builtin_bit_cast(half2v, __builtin_amdgcn_cvt_pkrtz(a, b));
}
__device__ __forceinline__ float fdot2f(half2v a, half2v b, float c) {
    return __builtin_amdgcn_fdot2(__builtin_bit_cast(fp16x2, a),
                                  __builtin_bit_cast(fp16x2, b), c, false);
}

// ---------------- K1: u,v precompute, transposed MFMA GEMM ----------------
__global__ __launch_bounds__(256) void precompute_uv(
    const float* __restrict__ emb, const float* __restrict__ fied,
    const float* __restrict__ W1, const float* __restrict__ b1,
    _Float16* __restrict__ u, _Float16* __restrict__ v,
    int n_nodes, int ntiles)
{
    const int lane = threadIdx.x & 63;
    const int q = lane >> 4;
    const int c = lane & 15;
    const int wid = blockIdx.x * (blockDim.x >> 6) + (threadIdx.x >> 6);
    const int nw  = gridDim.x * (blockDim.x >> 6);

    half8 Au[4][2], Av[4][2];
    #pragma unroll
    for (int t = 0; t < 4; ++t)
        #pragma unroll
        for (int ks = 0; ks < 2; ++ks)
            #pragma unroll
            for (int j = 0; j < 8; ++j) {
                int k = ks * 32 + q * 8 + j;
                Au[t][ks][j] = (_Float16)W1[k * HD + t * 16 + c];
                Av[t][ks][j] = (_Float16)W1[(64 + k) * HD + t * 16 + c];
            }
    f32x4 b1q[4], wsq[4], wdq[4];
    #pragma unroll
    for (int t = 0; t < 4; ++t) {
        b1q[t] = *(const f32x4*)(b1 + t * 16 + q * 4);
        wsq[t] = *(const f32x4*)(W1 + 128 * HD + t * 16 + q * 4);
        wdq[t] = *(const f32x4*)(W1 + 129 * HD + t * 16 + q * 4);
    }

    for (int tile = wid; tile < ntiles; tile += nw) {
        const int n0 = tile * 16;
        const int n  = n0 + c;
        int na = n; if (na >= n_nodes) na = n_nodes - 1;
        const float* rp = emb + (size_t)na * HD + q * 8;
        float8 a0 = *(const float8*)rp;
        float8 a1 = *(const float8*)(rp + 32);
        half8 B0 = __builtin_convertvector(a0, half8);
        half8 B1 = __builtin_convertvector(a1, half8);

        f32x4 aU[4] = {}, aV[4] = {};
        #pragma unroll
        for (int t = 0; t < 4; ++t) {
            aU[t] = __builtin_amdgcn_mfma_f32_16x16x32_f16(Au[t][0], B0, aU[t], 0, 0, 0);
            aU[t] = __builtin_amdgcn_mfma_f32_16x16x32_f16(Au[t][1], B1, aU[t], 0, 0, 0);
            aV[t] = __builtin_amdgcn_mfma_f32_16x16x32_f16(Av[t][0], B0, aV[t], 0, 0, 0);
            aV[t] = __builtin_amdgcn_mfma_f32_16x16x32_f16(Av[t][1], B1, aV[t], 0, 0, 0);
        }

        const float fv = fied[na];
        const bool ok = (n < n_nodes);
        #pragma unroll
        for (int t = 0; t < 4; ++t) {
            half4 hu, hv;
            #pragma unroll
            for (int r = 0; r < 4; ++r) {
                hu[r] = (_Float16)(aU[t][r] + b1q[t][r] + fv * wsq[t][r]);
                hv[r] = (_Float16)(aV[t][r] + fv * wdq[t][r]);
            }
            if (ok) {
                *(half4*)(u + (size_t)n * HD + t * 16 + q * 4) = hu;
                *(half4*)(v + (size_t)n * HD + t * 16 + q * 4) = hv;
            }
        }
    }
}

// ---------------- K2: per-edge MLP (layers 2+3) ----------------
// D' = W2^T . h1^T : A = W2^T (registers), B = h1^T (gathered).
// D' layout: col = c = edge, row = q*4+r = feature t*16+q*4+r.
__global__ __launch_bounds__(256) void edge_mlp(
    const _Float16* __restrict__ u, const _Float16* __restrict__ v,
    const int* __restrict__ src, const int* __restrict__ dst,
    const float* __restrict__ W2, const float* __restrict__ b2,
    const float* __restrict__ W3, const float* __restrict__ b3,
    float* __restrict__ out, int E, int ntiles)
{
    const int lane = threadIdx.x & 63;
    const int q = lane >> 4;
    const int c = lane & 15;
    const int wid = blockIdx.x * (blockDim.x >> 6) + (threadIdx.x >> 6);
    const int nw  = gridDim.x * (blockDim.x >> 6);

    // W2^T A-fragments in registers (R4-proven to keep the pipeline alive)
    half8 Af[4][2];
    #pragma unroll
    for (int t = 0; t < 4; ++t)
        #pragma unroll
        for (int ks = 0; ks < 2; ++ks)
            #pragma unroll
            for (int j = 0; j < 8; ++j) {
                int k = ks * 32 + q * 8 + j;
                Af[t][ks][j] = (_Float16)W2[k * HD + t * 16 + c];
            }
    // epilogue consts packed half2 (features f = t*16 + q*4 + r): 8 VGPRs
    half2v b2p[4][2], w3p[4][2];
    #pragma unroll
    for (int t = 0; t < 4; ++t) {
        int f = t * 16 + q * 4;
        b2p[t][0] = half2v{(_Float16)b2[f],     (_Float16)b2[f + 1]};
        b2p[t][1] = half2v{(_Float16)b2[f + 2], (_Float16)b2[f + 3]};
        w3p[t][0] = half2v{(_Float16)W3[f],     (_Float16)W3[f + 1]};
        w3p[t][1] = half2v{(_Float16)W3[f + 2], (_Float16)W3[f + 3]};
    }
    const float b3v = b3[0];

    auto eid = [&](int tile) {
        int t = tile; if (t >= ntiles) t = ntiles - 1;
        int e = t * 16 + c; if (e >= E) e = E - 1;
        return e;
    };
    auto issue = [&](int s, int d, half8& Ua, half8& Ub, half8& Va, half8& Vb) {
        const half8* up = (const half8*)(u + (unsigned)s * HD + q * 8);
        const half8* vp = (const half8*)(v + (unsigned)d * HD + q * 8);
        Ua = up[0]; Ub = up[4]; Va = vp[0]; Vb = vp[4];
    };
    auto compute_store = [&](int tile, half8 Ua, half8 Ub, half8 Va, half8 Vb) {
        half8 B0 = relu_h8(Ua + Va);
        half8 B1 = relu_h8(Ub + Vb);
        float p = 0.f;
        #pragma unroll
        for (int t = 0; t < 4; ++t) {
            f32x4 acc = {};
            acc = __builtin_amdgcn_mfma_f32_16x16x32_f16(Af[t][0], B0, acc, 0, 0, 0);
            acc = __builtin_amdgcn_mfma_f32_16x16x32_f16(Af[t][1], B1, acc, 0, 0, 0);
            half2v h0 = relu_h2(pkrtz(acc[0], acc[1]) + b2p[t][0]);
            half2v h1 = relu_h2(pkrtz(acc[2], acc[3]) + b2p[t][1]);
            p = fdot2f(h0, w3p[t][0], p);
            p = fdot2f(h1, w3p[t][1], p);
        }
        p += __shfl_xor(p, 16, 64);
        p += __shfl_xor(p, 32, 64);
        if (q == 0) {
            int e = tile * 16 + c;
            if (e < E) out[e] = p + b3v;
        }
    };

    const int stride = nw * 4;
    const int base0  = wid * 4;
    if (base0 >= ntiles) return;

    // ---- prologue: gathers for tiles base0..base0+3 ----
    half8 U0a,U0b,V0a,V0b, U1a,U1b,V1a,V1b, U2a,U2b,V2a,V2b, U3a,U3b,V3a,V3b;
    {
        int e0 = eid(base0), e1 = eid(base0+1), e2 = eid(base0+2), e3 = eid(base0+3);
        issue(src[e0], dst[e0], U0a, U0b, V0a, V0b);
        issue(src[e1], dst[e1], U1a, U1b, V1a, V1b);
        issue(src[e2], dst[e2], U2a, U2b, V2a, V2b);
        issue(src[e3], dst[e3], U3a, U3b, V3a, V3b);
    }
    // idx_cur: indices for the refills issued inside the NEXT loop body —
    // loaded a full iteration before use so refill addresses never wait on
    // young vmem ops (vmcnt retires oldest-first).
    int sc0, dc0, sc1, dc1, sc2, dc2, sc3, dc3;
    {
        int f0 = eid(base0+stride),   f1 = eid(base0+stride+1),
            f2 = eid(base0+stride+2), f3 = eid(base0+stride+3);
        sc0 = src[f0]; dc0 = dst[f0]; sc1 = src[f1]; dc1 = dst[f1];
        sc2 = src[f2]; dc2 = dst[f2]; sc3 = src[f3]; dc3 = dst[f3];
    }

    for (int base = base0; base < ntiles; base += stride) {
        const int g0 = eid(base + 2*stride),     g1 = eid(base + 2*stride + 1),
                  g2 = eid(base + 2*stride + 2), g3 = eid(base + 2*stride + 3);
        const int sn0 = src[g0], dn0 = dst[g0];
        const int sn1 = src[g1], dn1 = dst[g1];
        const int sn2 = src[g2], dn2 = dst[g2];
        const int sn3 = src[g3], dn3 = dst[g3];

        compute_store(base,     U0a, U0b, V0a, V0b);
        issue(sc0, dc0, U0a, U0b, V0a, V0b);
        compute_store(base + 1, U1a, U1b, V1a, V1b);
        issue(sc1, dc1, U1a, U1b, V1a, V1b);
        compute_store(base + 2, U2a, U2b, V2a, V2b);
        issue(sc2, dc2, U2a, U2b, V2a, V2b);
        compute_store(base + 3, U3a, U3b, V3a, V3b);
        issue(sc3, dc3, U3a, U3b, V3a, V3b);

        sc0 = sn0; dc0 = dn0; sc1 = sn1; dc1 = dn1;
        sc2 = sn2; dc2 = dn2; sc3 = sn3; dc3 = dn3;
    }
}

extern "C" void kernel_launch(void* const* d_in, const int* in_sizes, int n_in,
                              void* d_out, int out_size, void* d_ws, size_t ws_size,
                              hipStream_t stream) {
    const float* emb  = (const float*)d_in[0];
    const float* fied = (const float*)d_in[1];
    const float* W1   = (const float*)d_in[2];
    const float* b1   = (const float*)d_in[3];
    const float* W2   = (const float*)d_in[4];
    const float* b2   = (const float*)d_in[5];
    const float* W3   = (const float*)d_in[6];
    const float* b3   = (const float*)d_in[7];
    const int*   eidx = (const int*)d_in[8];

    const int n_nodes = in_sizes[1];
    const int E       = in_sizes[8] / 2;
    const int* srcp = eidx;
    const int* dstp = eidx + E;

    _Float16* u = (_Float16*)d_ws;                 // n_nodes*64 fp16
    _Float16* v = u + (size_t)n_nodes * HD;        // n_nodes*64 fp16

    const int ntilesN = (n_nodes + 15) / 16;
    precompute_uv<<<1024, 256, 0, stream>>>(emb, fied, W1, b1, u, v,
                                            n_nodes, ntilesN);

    const int ntilesE = (E + 15) / 16;
    edge_mlp<<<2048, 256, 0, stream>>>(u, v, srcp, dstp, W2, b2, W3, b3,
                                       (float*)d_out, E, ntilesE);
}